// Round 2
// baseline (657.986 us; speedup 1.0000x reference)
//
#include <hip/hip_runtime.h>

// LinkPredictor: score[e] = w2 . relu(W1 . concat(h[src[e]], h[dst[e]]) + b1) + b2
// N_NODES=100000, N_EDGES=1600000, D=128, K2=256, H=256
//
// R2: latency-bound fix. 512-thr blocks (8 waves x 32 cols -> B=64 VGPR/wave),
// launch_bounds(512,4) -> 16 waves/CU; gather pipelined 1 tile ahead in regs;
// LDS swizzle ROW_SH=280/HALF_SH=144 -> max 2-way bank aliasing; red dbuf.

#define NNODES 100000
#define E_TOTAL 1600000
#define D 128
#define K2 256
#define H 256

#define TILE_M 64
#define ROW_SH 280          // row stride in shorts = 140 dw (%32 = 12 -> 2-way read aliasing, free)
#define HALF_SH 144         // dst-half offset in shorts = 72 dw (write bases {0,8,12,20} mod 32)
#define NTILES (E_TOTAL / TILE_M)   // 25000
#define GRID 2500                   // 10 tiles per block

typedef short bf16x8 __attribute__((ext_vector_type(8)));
typedef float f32x4 __attribute__((ext_vector_type(4)));

__device__ __forceinline__ unsigned short f2bf(float f) {
    unsigned u = __float_as_uint(f);
    u += 0x7fff + ((u >> 16) & 1);   // round-to-nearest-even
    return (unsigned short)(u >> 16);
}

__global__ void cvt_kernel(const float* __restrict__ src, unsigned short* __restrict__ dst, int n4) {
    int i = blockIdx.x * blockDim.x + threadIdx.x;
    if (i >= n4) return;
    float4 v = ((const float4*)src)[i];
    ushort4 o;
    o.x = f2bf(v.x); o.y = f2bf(v.y); o.z = f2bf(v.z); o.w = f2bf(v.w);
    ((ushort4*)dst)[i] = o;
}

// 512 threads = 8 waves. Wave w owns hidden cols [32w, 32w+32).
__global__ __launch_bounds__(512, 4) void edge_mlp(
    const unsigned short* __restrict__ hbf,
    const int* __restrict__ srcE,
    const int* __restrict__ dstE,
    const unsigned short* __restrict__ w1bf,
    const float* __restrict__ b1,
    const float* __restrict__ w2,
    const float* __restrict__ b2p,
    float* __restrict__ out)
{
    __shared__ __align__(16) unsigned short X[TILE_M * ROW_SH];   // 35840 B
    __shared__ float red[2][TILE_M][9];                           // 4608 B (9: pad out-read conflicts)

    const int tid = threadIdx.x;
    const int wave = tid >> 6;        // 0..7
    const int lane = tid & 63;
    const int lane15 = lane & 15;
    const int quad = lane >> 4;

    // --- preload B fragments: lane holds W1[n][k..k+7]; n = 32*wave + nt*16 + lane15 ---
    bf16x8 B[8][2];
#pragma unroll
    for (int kit = 0; kit < 8; ++kit) {
#pragma unroll
        for (int nt = 0; nt < 2; ++nt) {
            int n = wave * 32 + nt * 16 + lane15;
            int k = kit * 32 + quad * 8;
            B[kit][nt] = *(const bf16x8*)(w1bf + n * K2 + k);
        }
    }

    float b1v[2], w2v[2];
#pragma unroll
    for (int nt = 0; nt < 2; ++nt) {
        int n = wave * 32 + nt * 16 + lane15;
        b1v[nt] = b1[n];
        w2v[nt] = w2[n];
    }
    const float b2 = *b2p;

    const int ghalf = tid >> 4;       // 0..31: half-row slot within a gather iteration
    const int gl = tid & 15;          // 16 lanes x 16B = one 256B half-row

    // --- prologue: gather tile blockIdx.x into regs ---
    bf16x8 v[4];
    {
        const int ebase = blockIdx.x * TILE_M;
#pragma unroll
        for (int it = 0; it < 4; ++it) {
            int hh = it * 32 + ghalf;                 // 0..127
            int e = ebase + (hh >> 1);
            int node = (hh & 1) ? dstE[e] : srcE[e];
            v[it] = *(const bf16x8*)(hbf + node * D + gl * 8);
        }
    }

    int buf = 0;
    int prev_ebase = -1;

    for (int tile = blockIdx.x; tile < NTILES; tile += GRID) {
        __syncthreads();   // X readers (prev MFMA) done; red[buf^1] written

        // --- store gathered regs -> LDS X ---
#pragma unroll
        for (int it = 0; it < 4; ++it) {
            int hh = it * 32 + ghalf;
            *(bf16x8*)&X[(hh >> 1) * ROW_SH + (hh & 1) * HALF_SH + gl * 8] = v[it];
        }
        // --- previous tile's final score write (wave 0 only, overlaps X-store) ---
        if (prev_ebase >= 0 && tid < TILE_M) {
            float s = b2;
#pragma unroll
            for (int w = 0; w < 8; ++w) s += red[buf ^ 1][tid][w];
            out[prev_ebase + tid] = s;
        }
        __syncthreads();   // X ready

        // --- prefetch next tile's gather (latency hidden under MFMA below) ---
        int ntile = tile + GRID;
        if (ntile < NTILES) {
            const int ebase = ntile * TILE_M;
#pragma unroll
            for (int it = 0; it < 4; ++it) {
                int hh = it * 32 + ghalf;
                int e = ebase + (hh >> 1);
                int node = (hh & 1) ? dstE[e] : srcE[e];
                v[it] = *(const bf16x8*)(hbf + node * D + gl * 8);
            }
        }

        // --- MFMA: hid[64 x 32-slice] per wave ---
        f32x4 acc[4][2];
        const f32x4 zero = {0.f, 0.f, 0.f, 0.f};
#pragma unroll
        for (int ms = 0; ms < 4; ++ms)
#pragma unroll
            for (int nt = 0; nt < 2; ++nt)
                acc[ms][nt] = zero;

#pragma unroll
        for (int kit = 0; kit < 8; ++kit) {
            int kof = (kit < 4) ? (kit * 32 + quad * 8)
                                : (HALF_SH + (kit - 4) * 32 + quad * 8);
            bf16x8 a[4];
#pragma unroll
            for (int ms = 0; ms < 4; ++ms)
                a[ms] = *(const bf16x8*)&X[(ms * 16 + lane15) * ROW_SH + kof];
#pragma unroll
            for (int ms = 0; ms < 4; ++ms)
#pragma unroll
                for (int nt = 0; nt < 2; ++nt)
                    acc[ms][nt] = __builtin_amdgcn_mfma_f32_16x16x32_bf16(
                        a[ms], B[kit][nt], acc[ms][nt], 0, 0, 0);
        }

        // --- epilogue: bias + relu + dot(w2), 16-lane reduce, stash partial ---
        // C/D layout: col = nt*16 + lane15, row = ms*16 + quad*4 + r
#pragma unroll
        for (int ms = 0; ms < 4; ++ms) {
#pragma unroll
            for (int r = 0; r < 4; ++r) {
                float p = 0.f;
#pragma unroll
                for (int nt = 0; nt < 2; ++nt) {
                    float hv = acc[ms][nt][r] + b1v[nt];
                    p = fmaf(fmaxf(hv, 0.f), w2v[nt], p);
                }
                p += __shfl_xor(p, 1, 16);
                p += __shfl_xor(p, 2, 16);
                p += __shfl_xor(p, 4, 16);
                p += __shfl_xor(p, 8, 16);
                if (lane15 == 0) red[buf][ms * 16 + quad * 4 + r][wave] = p;
            }
        }
        prev_ebase = tile * TILE_M;
        buf ^= 1;
    }

    // --- drain: last tile's score write ---
    __syncthreads();
    if (prev_ebase >= 0 && tid < TILE_M) {
        float s = b2;
#pragma unroll
        for (int w = 0; w < 8; ++w) s += red[buf ^ 1][tid][w];
        out[prev_ebase + tid] = s;
    }
}

extern "C" void kernel_launch(void* const* d_in, const int* in_sizes, int n_in,
                              void* d_out, int out_size, void* d_ws, size_t ws_size,
                              hipStream_t stream) {
    const float* h    = (const float*)d_in[0];
    const int*   srcE = (const int*)d_in[1];
    const int*   dstE = (const int*)d_in[2];
    const float* W1   = (const float*)d_in[3];
    const float* b1   = (const float*)d_in[4];
    const float* w2   = (const float*)d_in[5];
    const float* b2   = (const float*)d_in[6];
    float* out = (float*)d_out;

    unsigned short* hbf  = (unsigned short*)d_ws;               // 25.6 MB
    unsigned short* w1bf = hbf + (size_t)NNODES * D;            // 128 KB

    int n4h = NNODES * D / 4;
    cvt_kernel<<<(n4h + 255) / 256, 256, 0, stream>>>(h, hbf, n4h);
    int n4w = H * K2 / 4;
    cvt_kernel<<<(n4w + 255) / 256, 256, 0, stream>>>(W1, w1bf, n4w);

    edge_mlp<<<GRID, 512, 0, stream>>>(hbf, srcE, dstE, w1bf, b1, w2, b2, out);
}

// Round 3
// 645.447 us; speedup vs baseline: 1.0194x; 1.0194x over previous
//
#include <hip/hip_runtime.h>

// LinkPredictor: score[e] = w2 . relu(W1 . concat(h[src[e]], h[dst[e]]) + b1) + b2
// N_NODES=100000, N_EDGES=1600000, D=128, K2=256, H=256
//
// R3: R1 register geometry (4 waves x 64 cols, B=128 VGPR in-regs) + R2 pipelining
// (next-tile gather prefetched into regs under MFMA, dbuf red, LDS swizzle).
// launch_bounds(256,2): 256-VGPR cap -> NO spill (R2's launch_bounds(512,4)
// forced 64 VGPR and spilled B+acc to scratch: WRITE_SIZE 36->867 MB).

#define NNODES 100000
#define E_TOTAL 1600000
#define D 128
#define K2 256
#define H 256

#define TILE_M 64
#define ROW_SH 280          // row stride in shorts = 140 dw (%32=12): reads hit b128 minimum phasing
#define HALF_SH 144         // dst-half offset in shorts = 72 dw
#define NTILES (E_TOTAL / TILE_M)   // 25000
#define GRID 2500                   // 10 tiles per block, exact

typedef short bf16x8 __attribute__((ext_vector_type(8)));
typedef float f32x4 __attribute__((ext_vector_type(4)));

__device__ __forceinline__ unsigned short f2bf(float f) {
    unsigned u = __float_as_uint(f);
    u += 0x7fff + ((u >> 16) & 1);   // round-to-nearest-even
    return (unsigned short)(u >> 16);
}

// One launch converts both h (n4h float4-groups) and W1 (n4w groups) to bf16.
__global__ void cvt_kernel(const float* __restrict__ h, const float* __restrict__ w1,
                           unsigned short* __restrict__ hbf, unsigned short* __restrict__ w1bf,
                           int n4h, int n4w) {
    int i = blockIdx.x * blockDim.x + threadIdx.x;
    const float* s; unsigned short* d; int j;
    if (i < n4h) { s = h; d = hbf; j = i; }
    else if (i < n4h + n4w) { s = w1; d = w1bf; j = i - n4h; }
    else return;
    float4 v = ((const float4*)s)[j];
    ushort4 o;
    o.x = f2bf(v.x); o.y = f2bf(v.y); o.z = f2bf(v.z); o.w = f2bf(v.w);
    ((ushort4*)d)[j] = o;
}

// 256 threads = 4 waves. Wave w owns hidden cols [64w, 64w+64).
__global__ __launch_bounds__(256, 2) void edge_mlp(
    const unsigned short* __restrict__ hbf,
    const int* __restrict__ srcE,
    const int* __restrict__ dstE,
    const unsigned short* __restrict__ w1bf,
    const float* __restrict__ b1,
    const float* __restrict__ w2,
    const float* __restrict__ b2p,
    float* __restrict__ out)
{
    __shared__ __align__(16) unsigned short X[TILE_M * ROW_SH];   // 35840 B
    __shared__ float red[2][TILE_M][5];                           // 2560 B; stride 5 dw: 2-way max (free)

    const int tid = threadIdx.x;
    const int wave = tid >> 6;
    const int lane = tid & 63;
    const int lane15 = lane & 15;
    const int quad = lane >> 4;

    // --- preload B fragments (128 VGPRs/wave): lane holds W1[n][k..k+7] ---
    bf16x8 B[8][4];
#pragma unroll
    for (int kit = 0; kit < 8; ++kit) {
#pragma unroll
        for (int nt = 0; nt < 4; ++nt) {
            int n = wave * 64 + nt * 16 + lane15;
            int k = kit * 32 + quad * 8;
            B[kit][nt] = *(const bf16x8*)(w1bf + n * K2 + k);
        }
    }

    float b1v[4], w2v[4];
#pragma unroll
    for (int nt = 0; nt < 4; ++nt) {
        int n = wave * 64 + nt * 16 + lane15;
        b1v[nt] = b1[n];
        w2v[nt] = w2[n];
    }
    const float b2 = *b2p;

    const int ghalf = tid >> 4;   // 0..15: half-row slot per gather iteration
    const int gl = tid & 15;      // 16 lanes x 16B = one 256B half-row

    // --- prologue: gather first tile into regs ---
    bf16x8 v[8];
    {
        const int ebase = blockIdx.x * TILE_M;
#pragma unroll
        for (int it = 0; it < 8; ++it) {
            int hh = it * 16 + ghalf;                 // 0..127 half-rows
            int e = ebase + (hh >> 1);
            int node = (hh & 1) ? dstE[e] : srcE[e];
            v[it] = *(const bf16x8*)(hbf + node * D + gl * 8);
        }
    }

    int buf = 0;
    int prev_ebase = -1;

    for (int tile = blockIdx.x; tile < NTILES; tile += GRID) {
        __syncthreads();   // prev MFMA X-reads done; red[buf^1] fully written

        // --- store gathered regs -> LDS X ---
#pragma unroll
        for (int it = 0; it < 8; ++it) {
            int hh = it * 16 + ghalf;
            *(bf16x8*)&X[(hh >> 1) * ROW_SH + (hh & 1) * HALF_SH + gl * 8] = v[it];
        }
        // --- previous tile's score write (overlaps X-store) ---
        if (prev_ebase >= 0 && tid < TILE_M) {
            float s = b2;
#pragma unroll
            for (int w = 0; w < 4; ++w) s += red[buf ^ 1][tid][w];
            out[prev_ebase + tid] = s;
        }
        __syncthreads();   // X ready

        // --- prefetch next tile's gather (hides under MFMA below) ---
        int ntile = tile + GRID;
        if (ntile < NTILES) {
            const int ebase = ntile * TILE_M;
#pragma unroll
            for (int it = 0; it < 8; ++it) {
                int hh = it * 16 + ghalf;
                int e = ebase + (hh >> 1);
                int node = (hh & 1) ? dstE[e] : srcE[e];
                v[it] = *(const bf16x8*)(hbf + node * D + gl * 8);
            }
        }

        // --- MFMA: hid[64 x 64-slice] per wave ---
        f32x4 acc[4][4];
        const f32x4 zero = {0.f, 0.f, 0.f, 0.f};
#pragma unroll
        for (int ms = 0; ms < 4; ++ms)
#pragma unroll
            for (int nt = 0; nt < 4; ++nt)
                acc[ms][nt] = zero;

#pragma unroll
        for (int kit = 0; kit < 8; ++kit) {
            int kof = (kit < 4) ? (kit * 32 + quad * 8)
                                : (HALF_SH + (kit - 4) * 32 + quad * 8);
            bf16x8 a[4];
#pragma unroll
            for (int ms = 0; ms < 4; ++ms)
                a[ms] = *(const bf16x8*)&X[(ms * 16 + lane15) * ROW_SH + kof];
#pragma unroll
            for (int ms = 0; ms < 4; ++ms)
#pragma unroll
                for (int nt = 0; nt < 4; ++nt)
                    acc[ms][nt] = __builtin_amdgcn_mfma_f32_16x16x32_bf16(
                        a[ms], B[kit][nt], acc[ms][nt], 0, 0, 0);
        }

        // --- epilogue: bias + relu + dot(w2), 16-lane reduce -> red[buf] ---
        // C/D layout: col = nt*16 + lane15, row = ms*16 + quad*4 + r
#pragma unroll
        for (int ms = 0; ms < 4; ++ms) {
#pragma unroll
            for (int r = 0; r < 4; ++r) {
                float p = 0.f;
#pragma unroll
                for (int nt = 0; nt < 4; ++nt) {
                    float hv = acc[ms][nt][r] + b1v[nt];
                    p = fmaf(fmaxf(hv, 0.f), w2v[nt], p);
                }
                p += __shfl_xor(p, 1, 16);
                p += __shfl_xor(p, 2, 16);
                p += __shfl_xor(p, 4, 16);
                p += __shfl_xor(p, 8, 16);
                if (lane15 == 0) red[buf][ms * 16 + quad * 4 + r][wave] = p;
            }
        }
        prev_ebase = tile * TILE_M;
        buf ^= 1;
    }

    // --- drain: last tile's score write ---
    __syncthreads();
    if (prev_ebase >= 0 && tid < TILE_M) {
        float s = b2;
#pragma unroll
        for (int w = 0; w < 4; ++w) s += red[buf ^ 1][tid][w];
        out[prev_ebase + tid] = s;
    }
}

extern "C" void kernel_launch(void* const* d_in, const int* in_sizes, int n_in,
                              void* d_out, int out_size, void* d_ws, size_t ws_size,
                              hipStream_t stream) {
    const float* h    = (const float*)d_in[0];
    const int*   srcE = (const int*)d_in[1];
    const int*   dstE = (const int*)d_in[2];
    const float* W1   = (const float*)d_in[3];
    const float* b1   = (const float*)d_in[4];
    const float* w2   = (const float*)d_in[5];
    const float* b2   = (const float*)d_in[6];
    float* out = (float*)d_out;

    unsigned short* hbf  = (unsigned short*)d_ws;               // 25.6 MB
    unsigned short* w1bf = hbf + (size_t)NNODES * D;            // 128 KB

    int n4h = NNODES * D / 4;   // 3,200,000
    int n4w = H * K2 / 4;       // 16,384
    int n4 = n4h + n4w;
    cvt_kernel<<<(n4 + 255) / 256, 256, 0, stream>>>(h, W1, hbf, w1bf, n4h, n4w);

    edge_mlp<<<GRID, 256, 0, stream>>>(hbf, srcE, dstE, w1bf, b1, w2, b2, out);
}

// Round 4
// 401.603 us; speedup vs baseline: 1.6384x; 1.6072x over previous
//
#include <hip/hip_runtime.h>

// LinkPredictor: score[e] = w2 . relu(W1 . concat(h[src[e]], h[dst[e]]) + b1) + b2
// N_NODES=100000, N_EDGES=1600000, D=128, K2=256, H=256
//
// R4: kill the spill (R2/R3: compiler pins 128 VGPRs and spills any register
// prefetch -> 817 MB scratch traffic = exactly v[8] per tile). Gather now goes
// global->LDS directly via __builtin_amdgcn_global_load_lds (async, no VGPRs),
// double-buffered X, ONE barrier per tile. No padding possible with DMA ->
// XOR swizzle: 16B chunk c of row r stored at position c ^ (r&7).
// TILE_M=32 keeps X dbuf + red under the 64 KB static LDS cap.

#define NNODES 100000
#define E_TOTAL 1600000
#define D 128
#define K2 256
#define H 256

#define TILE_M 32
#define NTILES (E_TOTAL / TILE_M)   // 50000
#define GRID 2500                   // 20 tiles per block, exact

typedef short bf16x8 __attribute__((ext_vector_type(8)));
typedef float f32x4 __attribute__((ext_vector_type(4)));
typedef const __attribute__((address_space(1))) unsigned short* gas_t;
typedef __attribute__((address_space(3))) unsigned short* las_t;

#if defined(__has_attribute)
#if __has_attribute(amdgpu_waves_per_eu)
#define LB __launch_bounds__(256) __attribute__((amdgpu_waves_per_eu(2, 2)))
#else
#define LB __launch_bounds__(256, 2)
#endif
#else
#define LB __launch_bounds__(256, 2)
#endif

__device__ __forceinline__ unsigned short f2bf(float f) {
    unsigned u = __float_as_uint(f);
    u += 0x7fff + ((u >> 16) & 1);   // round-to-nearest-even
    return (unsigned short)(u >> 16);
}

// One launch converts both h and W1 to bf16.
__global__ void cvt_kernel(const float* __restrict__ h, const float* __restrict__ w1,
                           unsigned short* __restrict__ hbf, unsigned short* __restrict__ w1bf,
                           int n4h, int n4w) {
    int i = blockIdx.x * blockDim.x + threadIdx.x;
    const float* s; unsigned short* d; int j;
    if (i < n4h) { s = h; d = hbf; j = i; }
    else if (i < n4h + n4w) { s = w1; d = w1bf; j = i - n4h; }
    else return;
    float4 v = ((const float4*)s)[j];
    ushort4 o;
    o.x = f2bf(v.x); o.y = f2bf(v.y); o.z = f2bf(v.z); o.w = f2bf(v.w);
    ((ushort4*)d)[j] = o;
}

// 256 threads = 4 waves. Wave w owns hidden cols [64w, 64w+64).
// X layout (per buffer): 32 rows x 32 chunks of 16B; chunk content c at
// position p = c ^ (r & 7). DMA writes are lane-linear; reads are <=2-way.
__global__ LB void edge_mlp(
    const unsigned short* __restrict__ hbf,
    const int* __restrict__ srcE,
    const int* __restrict__ dstE,
    const unsigned short* __restrict__ w1bf,
    const float* __restrict__ b1,
    const float* __restrict__ w2,
    const float* __restrict__ b2p,
    float* __restrict__ out)
{
    __shared__ __align__(16) unsigned short X[2][TILE_M * K2];   // 32768 B
    __shared__ float red[2][TILE_M][5];                          // 1280 B

    const int tid = threadIdx.x;
    const int wave = tid >> 6;
    const int lane = tid & 63;
    const int lane15 = lane & 15;
    const int quad = lane >> 4;

    // --- preload B fragments (may live in AGPRs; MFMA reads A/B from AGPRs) ---
    bf16x8 B[8][4];
#pragma unroll
    for (int kit = 0; kit < 8; ++kit) {
#pragma unroll
        for (int nt = 0; nt < 4; ++nt) {
            int n = wave * 64 + nt * 16 + lane15;
            int k = kit * 32 + quad * 8;
            B[kit][nt] = *(const bf16x8*)(w1bf + n * K2 + k);
        }
    }

    float b1v[4], w2v[4];
#pragma unroll
    for (int nt = 0; nt < 4; ++nt) {
        int n = wave * 64 + nt * 16 + lane15;
        b1v[nt] = b1[n];
        w2v[nt] = w2[n];
    }
    const float b2 = *b2p;

    // --- per-thread gather constants ---
    // iteration it (0..3): slot A = it*256 + tid; row r = A>>5 = it*8 + (tid>>5);
    // pos p = tid&31; content chunk c = p ^ (r&7) = (tid&31) ^ ((tid>>5)&7).
    const int r_off = tid >> 5;                       // 0..7
    const int c = (tid & 31) ^ (r_off & 7);           // content chunk 0..31
    const int half = c >> 4;                          // 0 = src feats, 1 = dst feats
    const int fc = c & 15;                            // feature 16B-chunk
    const int* idx_base = half ? dstE : srcE;
    const int gshort = fc * 8;                        // short offset into node row

    const int t0 = blockIdx.x;
    int inode[4];

    // --- prologue: idx(t0) -> gather(t0)->X[0]; idx(t1) in flight ---
#pragma unroll
    for (int it = 0; it < 4; ++it)
        inode[it] = idx_base[t0 * TILE_M + it * 8 + r_off];
#pragma unroll
    for (int it = 0; it < 4; ++it)
        __builtin_amdgcn_global_load_lds(
            (gas_t)(hbf + inode[it] * D + gshort),
            (las_t)(&X[0][0] + it * 2048 + wave * 512), 16, 0, 0);
    {
        const int t1 = t0 + GRID;   // always < NTILES (20 tiles/block)
#pragma unroll
        for (int it = 0; it < 4; ++it)
            inode[it] = idx_base[t1 * TILE_M + it * 8 + r_off];
    }

    int buf = 0;
    int prev_eb = -1;

    for (int tile = t0; tile < NTILES; tile += GRID) {
        __syncthreads();   // vmcnt(0): gather(tile)->X[buf] landed; prev X[buf^1] reads done

        // --- issue async gather(tile+1) -> X[buf^1] (completes under MFMA) ---
        const int nt1 = tile + GRID;
        if (nt1 < NTILES) {
            unsigned short* Xn = &X[buf ^ 1][0];
#pragma unroll
            for (int it = 0; it < 4; ++it)
                __builtin_amdgcn_global_load_lds(
                    (gas_t)(hbf + inode[it] * D + gshort),
                    (las_t)(Xn + it * 2048 + wave * 512), 16, 0, 0);
        }
        // --- issue idx loads for tile+2 (drain at next barrier) ---
        const int nt2 = tile + 2 * GRID;
        if (nt2 < NTILES) {
            const int eb2 = nt2 * TILE_M;
#pragma unroll
            for (int it = 0; it < 4; ++it)
                inode[it] = idx_base[eb2 + it * 8 + r_off];
        }
        // --- deferred score write for previous tile ---
        if (prev_eb >= 0 && tid < TILE_M) {
            float s = b2;
#pragma unroll
            for (int w = 0; w < 4; ++w) s += red[buf ^ 1][tid][w];
            out[prev_eb + tid] = s;
        }

        // --- MFMA: hid[32 x 64-slice] per wave on X[buf] ---
        const unsigned short* Xc = &X[buf][0];
        f32x4 acc[2][4];
        const f32x4 zero = {0.f, 0.f, 0.f, 0.f};
#pragma unroll
        for (int ms = 0; ms < 2; ++ms)
#pragma unroll
            for (int nt = 0; nt < 4; ++nt)
                acc[ms][nt] = zero;

#pragma unroll
        for (int kit = 0; kit < 8; ++kit) {
            const int p8 = (((kit * 4 + quad) ^ (lane15 & 7))) * 8;   // swizzled read pos
            bf16x8 a[2];
#pragma unroll
            for (int ms = 0; ms < 2; ++ms)
                a[ms] = *(const bf16x8*)&Xc[(ms * 16 + lane15) * K2 + p8];
#pragma unroll
            for (int ms = 0; ms < 2; ++ms)
#pragma unroll
                for (int nt = 0; nt < 4; ++nt)
                    acc[ms][nt] = __builtin_amdgcn_mfma_f32_16x16x32_bf16(
                        a[ms], B[kit][nt], acc[ms][nt], 0, 0, 0);
        }

        // --- epilogue: bias + relu + dot(w2), 16-lane reduce -> red[buf] ---
        // C/D layout: col = nt*16 + lane15, row = ms*16 + quad*4 + r
#pragma unroll
        for (int ms = 0; ms < 2; ++ms) {
#pragma unroll
            for (int r = 0; r < 4; ++r) {
                float p = 0.f;
#pragma unroll
                for (int nt = 0; nt < 4; ++nt) {
                    float hv = acc[ms][nt][r] + b1v[nt];
                    p = fmaf(fmaxf(hv, 0.f), w2v[nt], p);
                }
                p += __shfl_xor(p, 1, 16);
                p += __shfl_xor(p, 2, 16);
                p += __shfl_xor(p, 4, 16);
                p += __shfl_xor(p, 8, 16);
                if (lane15 == 0) red[buf][ms * 16 + quad * 4 + r][wave] = p;
            }
        }
        prev_eb = tile * TILE_M;
        buf ^= 1;
    }

    // --- drain: last tile's score write ---
    __syncthreads();
    if (prev_eb >= 0 && tid < TILE_M) {
        float s = b2;
#pragma unroll
        for (int w = 0; w < 4; ++w) s += red[buf ^ 1][tid][w];
        out[prev_eb + tid] = s;
    }
}

extern "C" void kernel_launch(void* const* d_in, const int* in_sizes, int n_in,
                              void* d_out, int out_size, void* d_ws, size_t ws_size,
                              hipStream_t stream) {
    const float* h    = (const float*)d_in[0];
    const int*   srcE = (const int*)d_in[1];
    const int*   dstE = (const int*)d_in[2];
    const float* W1   = (const float*)d_in[3];
    const float* b1   = (const float*)d_in[4];
    const float* w2   = (const float*)d_in[5];
    const float* b2   = (const float*)d_in[6];
    float* out = (float*)d_out;

    unsigned short* hbf  = (unsigned short*)d_ws;               // 25.6 MB
    unsigned short* w1bf = hbf + (size_t)NNODES * D;            // 128 KB

    int n4h = NNODES * D / 4;   // 3,200,000
    int n4w = H * K2 / 4;       // 16,384
    int n4 = n4h + n4w;
    cvt_kernel<<<(n4 + 255) / 256, 256, 0, stream>>>(h, W1, hbf, w1bf, n4h, n4w);

    edge_mlp<<<GRID, 256, 0, stream>>>(hbf, srcE, dstE, w1bf, b1, w2, b2, out);
}

// Round 5
// 394.548 us; speedup vs baseline: 1.6677x; 1.0179x over previous
//
#include <hip/hip_runtime.h>

// LinkPredictor: score[e] = w2 . relu(W1 . concat(h[src[e]], h[dst[e]]) + b1) + b2
// N_NODES=100000, N_EDGES=1600000, D=128, K2=256, H=256
//
// R5: algorithm restructure. hid = relu(Us[src] + Ud[dst] + b1) with
// Us = h.W1s^T, Ud = h.W1d^T precomputed densely per NODE (26 GFLOP, no
// gather). Edge pass becomes pure streaming gather+VALU (no MFMA/LDS/
// barriers) at full occupancy. R4's tile structure capped at MfmaUtil 27%
// (89 us matrix busy vs 335 us wall: barrier drains + 2-blocks/CU cap).
// b1 folded into Us at store. Fallback to R4 path if ws < 102.4 MB.

#define NNODES 100000
#define E_TOTAL 1600000
#define D 128
#define K2 256
#define H 256

typedef short bf16x8 __attribute__((ext_vector_type(8)));
typedef short bf16x4 __attribute__((ext_vector_type(4)));
typedef float f32x4 __attribute__((ext_vector_type(4)));
typedef const __attribute__((address_space(1))) unsigned short* gas_t;
typedef __attribute__((address_space(3))) unsigned short* las_t;

#if defined(__has_attribute)
#if __has_attribute(amdgpu_waves_per_eu)
#define LB __launch_bounds__(256) __attribute__((amdgpu_waves_per_eu(2, 2)))
#else
#define LB __launch_bounds__(256, 2)
#endif
#else
#define LB __launch_bounds__(256, 2)
#endif

__device__ __forceinline__ unsigned short f2bf(float f) {
    unsigned u = __float_as_uint(f);
    u += 0x7fff + ((u >> 16) & 1);   // round-to-nearest-even
    return (unsigned short)(u >> 16);
}
__device__ __forceinline__ float bf2f(unsigned short s) {
    return __uint_as_float((unsigned)s << 16);
}

// ============================ R5 primary path ============================

// Per-node projection: Us[v][n] = sum_k W1[n][k] h[v][k] (+ b1[n] folded),
// Ud[v][n] = sum_k W1[n][128+k] h[v][k]. 64 node-rows per block, K=128 in
// one shot, 4 waves x 64 cols. h staged fp32->bf16 through LDS (pad 136).
__global__ LB void u_gemm(
    const float* __restrict__ h,
    const float* __restrict__ W1,
    const float* __restrict__ b1,
    unsigned short* __restrict__ Us,
    unsigned short* __restrict__ Ud)
{
    __shared__ __align__(16) unsigned short A[64 * 136];   // 17408 B

    const int tid = threadIdx.x;
    const int wave = tid >> 6;
    const int lane = tid & 63;
    const int l15 = lane & 15;
    const int quad = lane >> 4;

    const int r0 = blockIdx.x * 64;
    int rows = NNODES - r0; if (rows > 64) rows = 64;

    // --- stage h tile: rows*128 fp32, fully coalesced float4, cvt->bf16 LDS ---
    const float4* hf4 = (const float4*)(h + (size_t)r0 * D);
    const int lim = rows * 32;
#pragma unroll
    for (int i = 0; i < 8; ++i) {
        int j = tid + i * 256;
        if (j < lim) {
            float4 v = hf4[j];
            bf16x4 b;
            b[0] = (short)f2bf(v.x); b[1] = (short)f2bf(v.y);
            b[2] = (short)f2bf(v.z); b[3] = (short)f2bf(v.w);
            *(bf16x4*)&A[(j >> 5) * 136 + (j & 31) * 4] = b;
        }
    }
    __syncthreads();

#pragma unroll
    for (int half = 0; half < 2; ++half) {
        const int koff = half * 128;
        unsigned short* U = half ? Ud : Us;

        // B fragments: W1[n][koff + kit*32 + quad*8 ..+8], fp32 load + cvt
        bf16x8 B[4][4];
        float bias[4];
#pragma unroll
        for (int nt = 0; nt < 4; ++nt) {
            const int n = wave * 64 + nt * 16 + l15;
            bias[nt] = half ? 0.f : b1[n];
#pragma unroll
            for (int kit = 0; kit < 4; ++kit) {
                const float* wp = W1 + (size_t)n * K2 + koff + kit * 32 + quad * 8;
                float4 x = *(const float4*)wp;
                float4 y = *(const float4*)(wp + 4);
                bf16x8 f;
                f[0] = (short)f2bf(x.x); f[1] = (short)f2bf(x.y);
                f[2] = (short)f2bf(x.z); f[3] = (short)f2bf(x.w);
                f[4] = (short)f2bf(y.x); f[5] = (short)f2bf(y.y);
                f[6] = (short)f2bf(y.z); f[7] = (short)f2bf(y.w);
                B[kit][nt] = f;
            }
        }

        f32x4 acc[4][4];
        const f32x4 zero = {0.f, 0.f, 0.f, 0.f};
#pragma unroll
        for (int ms = 0; ms < 4; ++ms)
#pragma unroll
            for (int nt = 0; nt < 4; ++nt)
                acc[ms][nt] = zero;

#pragma unroll
        for (int kit = 0; kit < 4; ++kit) {
            bf16x8 a[4];
#pragma unroll
            for (int ms = 0; ms < 4; ++ms)
                a[ms] = *(const bf16x8*)&A[(ms * 16 + l15) * 136 + kit * 32 + quad * 8];
#pragma unroll
            for (int ms = 0; ms < 4; ++ms)
#pragma unroll
                for (int nt = 0; nt < 4; ++nt)
                    acc[ms][nt] = __builtin_amdgcn_mfma_f32_16x16x32_bf16(
                        a[ms], B[kit][nt], acc[ms][nt], 0, 0, 0);
        }

        // store: row m = ms*16+quad*4+r, col n = wave*64+nt*16+l15
#pragma unroll
        for (int ms = 0; ms < 4; ++ms) {
#pragma unroll
            for (int r = 0; r < 4; ++r) {
                const int m = ms * 16 + quad * 4 + r;
                if (m < rows) {
                    unsigned short* rowp = U + (size_t)(r0 + m) * H + wave * 64;
#pragma unroll
                    for (int nt = 0; nt < 4; ++nt)
                        rowp[nt * 16 + l15] = f2bf(acc[ms][nt][r] + bias[nt]);
                }
            }
        }
    }
}

// Edge pass: quarter-wave (16 lanes) per edge; lane l covers hidden cols
// [16l, 16l+16). score = w2 . relu(Us[src] + Ud[dst]) + b2. No LDS, no sync.
__global__ __launch_bounds__(256) void edge_score(
    const unsigned short* __restrict__ Us,
    const unsigned short* __restrict__ Ud,
    const int* __restrict__ srcE,
    const int* __restrict__ dstE,
    const float* __restrict__ w2,
    const float* __restrict__ b2p,
    float* __restrict__ out)
{
    const int gt = blockIdx.x * 256 + threadIdx.x;
    const int l = gt & 15;
    const int q = gt >> 4;
    const int Q = (gridDim.x * 256) >> 4;

    float w2v[16];
#pragma unroll
    for (int j = 0; j < 16; ++j) w2v[j] = w2[l * 16 + j];
    const float b2 = *b2p;

    for (int e = q; e < E_TOTAL; e += Q) {
        const int s = srcE[e];
        const int d = dstE[e];
        const bf16x8* us = (const bf16x8*)(Us + (size_t)s * H + l * 16);
        const bf16x8* ud = (const bf16x8*)(Ud + (size_t)d * H + l * 16);
        bf16x8 u0 = us[0], u1 = us[1];
        bf16x8 v0 = ud[0], v1 = ud[1];

        float acc = 0.f;
#pragma unroll
        for (int j = 0; j < 8; ++j) {
            float hv = bf2f((unsigned short)u0[j]) + bf2f((unsigned short)v0[j]);
            acc = fmaf(fmaxf(hv, 0.f), w2v[j], acc);
        }
#pragma unroll
        for (int j = 0; j < 8; ++j) {
            float hv = bf2f((unsigned short)u1[j]) + bf2f((unsigned short)v1[j]);
            acc = fmaf(fmaxf(hv, 0.f), w2v[j + 8], acc);
        }
        acc += __shfl_xor(acc, 1, 16);
        acc += __shfl_xor(acc, 2, 16);
        acc += __shfl_xor(acc, 4, 16);
        acc += __shfl_xor(acc, 8, 16);
        if (l == 0) out[e] = acc + b2;
    }
}

// ======================= R4 fallback (ws too small) ======================

#define TILE_M 32
#define NTILES (E_TOTAL / TILE_M)   // 50000
#define GRID 2500                   // 20 tiles per block

__global__ void cvt_kernel(const float* __restrict__ h, const float* __restrict__ w1,
                           unsigned short* __restrict__ hbf, unsigned short* __restrict__ w1bf,
                           int n4h, int n4w) {
    int i = blockIdx.x * blockDim.x + threadIdx.x;
    const float* s; unsigned short* d; int j;
    if (i < n4h) { s = h; d = hbf; j = i; }
    else if (i < n4h + n4w) { s = w1; d = w1bf; j = i - n4h; }
    else return;
    float4 v = ((const float4*)s)[j];
    ushort4 o;
    o.x = f2bf(v.x); o.y = f2bf(v.y); o.z = f2bf(v.z); o.w = f2bf(v.w);
    ((ushort4*)d)[j] = o;
}

__global__ LB void edge_mlp(
    const unsigned short* __restrict__ hbf,
    const int* __restrict__ srcE,
    const int* __restrict__ dstE,
    const unsigned short* __restrict__ w1bf,
    const float* __restrict__ b1,
    const float* __restrict__ w2,
    const float* __restrict__ b2p,
    float* __restrict__ out)
{
    __shared__ __align__(16) unsigned short X[2][TILE_M * K2];
    __shared__ float red[2][TILE_M][5];

    const int tid = threadIdx.x;
    const int wave = tid >> 6;
    const int lane = tid & 63;
    const int lane15 = lane & 15;
    const int quad = lane >> 4;

    bf16x8 B[8][4];
#pragma unroll
    for (int kit = 0; kit < 8; ++kit)
#pragma unroll
        for (int nt = 0; nt < 4; ++nt) {
            int n = wave * 64 + nt * 16 + lane15;
            int k = kit * 32 + quad * 8;
            B[kit][nt] = *(const bf16x8*)(w1bf + n * K2 + k);
        }

    float b1v[4], w2v[4];
#pragma unroll
    for (int nt = 0; nt < 4; ++nt) {
        int n = wave * 64 + nt * 16 + lane15;
        b1v[nt] = b1[n];
        w2v[nt] = w2[n];
    }
    const float b2 = *b2p;

    const int r_off = tid >> 5;
    const int c = (tid & 31) ^ (r_off & 7);
    const int half = c >> 4;
    const int fc = c & 15;
    const int* idx_base = half ? dstE : srcE;
    const int gshort = fc * 8;

    const int t0 = blockIdx.x;
    int inode[4];

#pragma unroll
    for (int it = 0; it < 4; ++it)
        inode[it] = idx_base[t0 * TILE_M + it * 8 + r_off];
#pragma unroll
    for (int it = 0; it < 4; ++it)
        __builtin_amdgcn_global_load_lds(
            (gas_t)(hbf + inode[it] * D + gshort),
            (las_t)(&X[0][0] + it * 2048 + wave * 512), 16, 0, 0);
    {
        const int t1 = t0 + GRID;
#pragma unroll
        for (int it = 0; it < 4; ++it)
            inode[it] = idx_base[t1 * TILE_M + it * 8 + r_off];
    }

    int buf = 0;
    int prev_eb = -1;

    for (int tile = t0; tile < NTILES; tile += GRID) {
        __syncthreads();

        const int nt1 = tile + GRID;
        if (nt1 < NTILES) {
            unsigned short* Xn = &X[buf ^ 1][0];
#pragma unroll
            for (int it = 0; it < 4; ++it)
                __builtin_amdgcn_global_load_lds(
                    (gas_t)(hbf + inode[it] * D + gshort),
                    (las_t)(Xn + it * 2048 + wave * 512), 16, 0, 0);
        }
        const int nt2 = tile + 2 * GRID;
        if (nt2 < NTILES) {
            const int eb2 = nt2 * TILE_M;
#pragma unroll
            for (int it = 0; it < 4; ++it)
                inode[it] = idx_base[eb2 + it * 8 + r_off];
        }
        if (prev_eb >= 0 && tid < TILE_M) {
            float s = b2;
#pragma unroll
            for (int w = 0; w < 4; ++w) s += red[buf ^ 1][tid][w];
            out[prev_eb + tid] = s;
        }

        const unsigned short* Xc = &X[buf][0];
        f32x4 acc[2][4];
        const f32x4 zero = {0.f, 0.f, 0.f, 0.f};
#pragma unroll
        for (int ms = 0; ms < 2; ++ms)
#pragma unroll
            for (int nt = 0; nt < 4; ++nt)
                acc[ms][nt] = zero;

#pragma unroll
        for (int kit = 0; kit < 8; ++kit) {
            const int p8 = (((kit * 4 + quad) ^ (lane15 & 7))) * 8;
            bf16x8 a[2];
#pragma unroll
            for (int ms = 0; ms < 2; ++ms)
                a[ms] = *(const bf16x8*)&Xc[(ms * 16 + lane15) * K2 + p8];
#pragma unroll
            for (int ms = 0; ms < 2; ++ms)
#pragma unroll
                for (int nt = 0; nt < 4; ++nt)
                    acc[ms][nt] = __builtin_amdgcn_mfma_f32_16x16x32_bf16(
                        a[ms], B[kit][nt], acc[ms][nt], 0, 0, 0);
        }

#pragma unroll
        for (int ms = 0; ms < 2; ++ms)
#pragma unroll
            for (int r = 0; r < 4; ++r) {
                float p = 0.f;
#pragma unroll
                for (int nt = 0; nt < 4; ++nt) {
                    float hv = acc[ms][nt][r] + b1v[nt];
                    p = fmaf(fmaxf(hv, 0.f), w2v[nt], p);
                }
                p += __shfl_xor(p, 1, 16);
                p += __shfl_xor(p, 2, 16);
                p += __shfl_xor(p, 4, 16);
                p += __shfl_xor(p, 8, 16);
                if (lane15 == 0) red[buf][ms * 16 + quad * 4 + r][wave] = p;
            }
        prev_eb = tile * TILE_M;
        buf ^= 1;
    }

    __syncthreads();
    if (prev_eb >= 0 && tid < TILE_M) {
        float s = b2;
#pragma unroll
        for (int w = 0; w < 4; ++w) s += red[buf ^ 1][tid][w];
        out[prev_eb + tid] = s;
    }
}

// ================================ launch ================================

extern "C" void kernel_launch(void* const* d_in, const int* in_sizes, int n_in,
                              void* d_out, int out_size, void* d_ws, size_t ws_size,
                              hipStream_t stream) {
    const float* h    = (const float*)d_in[0];
    const int*   srcE = (const int*)d_in[1];
    const int*   dstE = (const int*)d_in[2];
    const float* W1   = (const float*)d_in[3];
    const float* b1   = (const float*)d_in[4];
    const float* w2   = (const float*)d_in[5];
    const float* b2   = (const float*)d_in[6];
    float* out = (float*)d_out;

    const size_t planeElems = (size_t)NNODES * H;        // 25.6M
    const size_t need = planeElems * 2 * sizeof(unsigned short);  // 102.4 MB

    if (ws_size >= need) {
        // R5 primary: precompute Us/Ud, then streaming edge pass
        unsigned short* Us = (unsigned short*)d_ws;
        unsigned short* Ud = Us + planeElems;
        u_gemm<<<(NNODES + 63) / 64, 256, 0, stream>>>(h, W1, b1, Us, Ud);
        edge_score<<<4096, 256, 0, stream>>>(Us, Ud, srcE, dstE, w2, b2, out);
    } else {
        // R4 fallback: fused gather+MFMA pipeline (proven, ~402 us)
        unsigned short* hbf  = (unsigned short*)d_ws;
        unsigned short* w1bf = hbf + (size_t)NNODES * D;
        int n4h = NNODES * D / 4;
        int n4w = H * K2 / 4;
        int n4 = n4h + n4w;
        cvt_kernel<<<(n4 + 255) / 256, 256, 0, stream>>>(h, W1, hbf, w1bf, n4h, n4w);
        edge_mlp<<<GRID, 256, 0, stream>>>(hbf, srcE, dstE, w1bf, b1, w2, b2, out);
    }
}

// Round 6
// 385.113 us; speedup vs baseline: 1.7086x; 1.0245x over previous
//
#include <hip/hip_runtime.h>

// LinkPredictor: score[e] = w2 . relu(W1 . concat(h[src[e]], h[dst[e]]) + b1) + b2
// N_NODES=100000, N_EDGES=1600000, D=128, K2=256, H=256
//
// R6: R5 factorization kept (Us = h.W1s^T + b1, Ud = h.W1d^T; edge pass =
// gather+VALU). Fixes:
//  - u_gemm (~165 us hidden in R5): U stores were 2B/lane scalar (102 MB of
//    32B-segment RMW). Now C-tile bounces through LDS (stride-268 swizzle,
//    all phases <=2-way) and drains as coalesced dwordx4.
//  - edge_score (229 us, latency-bound: VALU 28%, 4 loads/lane in flight):
//    4 edges per 16-lane group per iter -> 16 outstanding row-loads/lane,
//    int4 idx broadcast, float4 packed out-store.

#define NNODES 100000
#define E_TOTAL 1600000
#define D 128
#define K2 256
#define H 256

typedef short bf16x8 __attribute__((ext_vector_type(8)));
typedef short bf16x4 __attribute__((ext_vector_type(4)));
typedef float f32x4 __attribute__((ext_vector_type(4)));
typedef const __attribute__((address_space(1))) unsigned short* gas_t;
typedef __attribute__((address_space(3))) unsigned short* las_t;

__device__ __forceinline__ unsigned short f2bf(float f) {
    unsigned u = __float_as_uint(f);
    u += 0x7fff + ((u >> 16) & 1);   // round-to-nearest-even
    return (unsigned short)(u >> 16);
}
__device__ __forceinline__ float bf2f(unsigned short s) {
    return __uint_as_float((unsigned)s << 16);
}

// ============================ R6 primary path ============================

// Per-node projection. 64 node-rows per block, 4 waves x 64 cols, two K=128
// halves. Stores staged through LDS S (stride 268 shorts: ds-write quads hit
// disjoint bank groups) then drained as dwordx4 (full 64B lines).
__global__ __launch_bounds__(256, 2) void u_gemm(
    const float* __restrict__ h,
    const float* __restrict__ W1,
    const float* __restrict__ b1,
    unsigned short* __restrict__ Us,
    unsigned short* __restrict__ Ud)
{
    __shared__ __align__(16) unsigned short A[64 * 136];   // 17408 B
    __shared__ __align__(16) unsigned short S[64 * 268];   // 34304 B (52 KB total)

    const int tid = threadIdx.x;
    const int wave = tid >> 6;
    const int lane = tid & 63;
    const int l15 = lane & 15;
    const int quad = lane >> 4;

    const int r0 = blockIdx.x * 64;
    int rows = NNODES - r0; if (rows > 64) rows = 64;

    // --- stage h tile: rows*128 fp32, coalesced float4, cvt->bf16 LDS ---
    const float4* hf4 = (const float4*)(h + (size_t)r0 * D);
    const int lim = rows * 32;
#pragma unroll
    for (int i = 0; i < 8; ++i) {
        int j = tid + i * 256;
        if (j < lim) {
            float4 v = hf4[j];
            bf16x4 b;
            b[0] = (short)f2bf(v.x); b[1] = (short)f2bf(v.y);
            b[2] = (short)f2bf(v.z); b[3] = (short)f2bf(v.w);
            *(bf16x4*)&A[(j >> 5) * 136 + (j & 31) * 4] = b;
        }
    }
    __syncthreads();

    for (int half = 0; half < 2; ++half) {
        const int koff = half * 128;
        unsigned short* U = half ? Ud : Us;

        // B fragments: W1[n][koff + kit*32 + quad*8 ..+8], fp32 load + cvt
        bf16x8 B[4][4];
        float bias[4];
#pragma unroll
        for (int nt = 0; nt < 4; ++nt) {
            const int n = wave * 64 + nt * 16 + l15;
            bias[nt] = half ? 0.f : b1[n];
#pragma unroll
            for (int kit = 0; kit < 4; ++kit) {
                const float* wp = W1 + (size_t)n * K2 + koff + kit * 32 + quad * 8;
                float4 x = *(const float4*)wp;
                float4 y = *(const float4*)(wp + 4);
                bf16x8 f;
                f[0] = (short)f2bf(x.x); f[1] = (short)f2bf(x.y);
                f[2] = (short)f2bf(x.z); f[3] = (short)f2bf(x.w);
                f[4] = (short)f2bf(y.x); f[5] = (short)f2bf(y.y);
                f[6] = (short)f2bf(y.z); f[7] = (short)f2bf(y.w);
                B[kit][nt] = f;
            }
        }

        f32x4 acc[4][4];
        const f32x4 zero = {0.f, 0.f, 0.f, 0.f};
#pragma unroll
        for (int ms = 0; ms < 4; ++ms)
#pragma unroll
            for (int nt = 0; nt < 4; ++nt)
                acc[ms][nt] = zero;

#pragma unroll
        for (int kit = 0; kit < 4; ++kit) {
            bf16x8 a[4];
#pragma unroll
            for (int ms = 0; ms < 4; ++ms)
                a[ms] = *(const bf16x8*)&A[(ms * 16 + l15) * 136 + kit * 32 + quad * 8];
#pragma unroll
            for (int ms = 0; ms < 4; ++ms)
#pragma unroll
                for (int nt = 0; nt < 4; ++nt)
                    acc[ms][nt] = __builtin_amdgcn_mfma_f32_16x16x32_bf16(
                        a[ms], B[kit][nt], acc[ms][nt], 0, 0, 0);
        }

        // C-layout: row m = ms*16+quad*4+r, col n = wave*64+nt*16+l15.
        // Stage to S[m*268 + n] (2B ds_write; quads land on disjoint banks).
        if (half) __syncthreads();   // prior drain's S reads complete
#pragma unroll
        for (int ms = 0; ms < 4; ++ms)
#pragma unroll
            for (int r = 0; r < 4; ++r) {
                const int m = ms * 16 + quad * 4 + r;
#pragma unroll
                for (int nt = 0; nt < 4; ++nt)
                    S[m * 268 + wave * 64 + nt * 16 + l15] =
                        f2bf(acc[ms][nt][r] + bias[nt]);
            }
        __syncthreads();

        // Drain: 64 rows x 256 cols bf16 -> global, dwordx4 coalesced.
#pragma unroll
        for (int i = 0; i < 8; ++i) {
            const int j = i * 256 + tid;          // 0..2047
            const int row = j >> 5;
            const int cc = j & 31;
            if (row < rows) {
                bf16x8 vv = *(const bf16x8*)&S[row * 268 + cc * 8];
                *(bf16x8*)(U + (size_t)(r0 + row) * H + cc * 8) = vv;
            }
        }
    }
}

// Edge pass: 16-lane group processes 4 consecutive edges per iteration.
// Lane l covers hidden cols [16l,16l+16). 16 row-loads in flight per lane.
__global__ __launch_bounds__(256) void edge_score(
    const unsigned short* __restrict__ Us,
    const unsigned short* __restrict__ Ud,
    const int* __restrict__ srcE,
    const int* __restrict__ dstE,
    const float* __restrict__ w2,
    const float* __restrict__ b2p,
    float* __restrict__ out)
{
    const int gt = blockIdx.x * 256 + threadIdx.x;
    const int l = gt & 15;
    const int q = gt >> 4;
    const int Q = (gridDim.x * 256) >> 4;
    const int NGRP = E_TOTAL / 4;   // 400000

    float w2v[16];
#pragma unroll
    for (int j = 0; j < 16; ++j) w2v[j] = w2[l * 16 + j];
    const float b2 = *b2p;

    for (int g = q; g < NGRP; g += Q) {
        const int e0 = g * 4;
        const int4 s4 = *(const int4*)(srcE + e0);   // broadcast (same addr all lanes)
        const int4 d4 = *(const int4*)(dstE + e0);
        const int sv[4] = {s4.x, s4.y, s4.z, s4.w};
        const int dv[4] = {d4.x, d4.y, d4.z, d4.w};

        bf16x8 u[4][2], v[4][2];
#pragma unroll
        for (int k = 0; k < 4; ++k) {
            const bf16x8* us = (const bf16x8*)(Us + (size_t)sv[k] * H + l * 16);
            const bf16x8* ud = (const bf16x8*)(Ud + (size_t)dv[k] * H + l * 16);
            u[k][0] = us[0]; u[k][1] = us[1];
            v[k][0] = ud[0]; v[k][1] = ud[1];
        }

        float4 res;
        float* resp = (float*)&res;
#pragma unroll
        for (int k = 0; k < 4; ++k) {
            float acc = 0.f;
#pragma unroll
            for (int j = 0; j < 8; ++j) {
                float hv = bf2f((unsigned short)u[k][0][j]) + bf2f((unsigned short)v[k][0][j]);
                acc = fmaf(fmaxf(hv, 0.f), w2v[j], acc);
            }
#pragma unroll
            for (int j = 0; j < 8; ++j) {
                float hv = bf2f((unsigned short)u[k][1][j]) + bf2f((unsigned short)v[k][1][j]);
                acc = fmaf(fmaxf(hv, 0.f), w2v[j + 8], acc);
            }
            acc += __shfl_xor(acc, 1, 16);
            acc += __shfl_xor(acc, 2, 16);
            acc += __shfl_xor(acc, 4, 16);
            acc += __shfl_xor(acc, 8, 16);
            resp[k] = acc + b2;
        }
        if (l == 0) *(float4*)(out + e0) = res;
    }
}

// ======================= R4 fallback (ws too small) ======================

#define TILE_M 32
#define NTILES (E_TOTAL / TILE_M)   // 50000
#define GRID 2500                   // 20 tiles per block

#if defined(__has_attribute)
#if __has_attribute(amdgpu_waves_per_eu)
#define LB __launch_bounds__(256) __attribute__((amdgpu_waves_per_eu(2, 2)))
#else
#define LB __launch_bounds__(256, 2)
#endif
#else
#define LB __launch_bounds__(256, 2)
#endif

__global__ void cvt_kernel(const float* __restrict__ h, const float* __restrict__ w1,
                           unsigned short* __restrict__ hbf, unsigned short* __restrict__ w1bf,
                           int n4h, int n4w) {
    int i = blockIdx.x * blockDim.x + threadIdx.x;
    const float* s; unsigned short* d; int j;
    if (i < n4h) { s = h; d = hbf; j = i; }
    else if (i < n4h + n4w) { s = w1; d = w1bf; j = i - n4h; }
    else return;
    float4 v = ((const float4*)s)[j];
    ushort4 o;
    o.x = f2bf(v.x); o.y = f2bf(v.y); o.z = f2bf(v.z); o.w = f2bf(v.w);
    ((ushort4*)d)[j] = o;
}

__global__ LB void edge_mlp(
    const unsigned short* __restrict__ hbf,
    const int* __restrict__ srcE,
    const int* __restrict__ dstE,
    const unsigned short* __restrict__ w1bf,
    const float* __restrict__ b1,
    const float* __restrict__ w2,
    const float* __restrict__ b2p,
    float* __restrict__ out)
{
    __shared__ __align__(16) unsigned short X[2][TILE_M * K2];
    __shared__ float red[2][TILE_M][5];

    const int tid = threadIdx.x;
    const int wave = tid >> 6;
    const int lane = tid & 63;
    const int lane15 = lane & 15;
    const int quad = lane >> 4;

    bf16x8 B[8][4];
#pragma unroll
    for (int kit = 0; kit < 8; ++kit)
#pragma unroll
        for (int nt = 0; nt < 4; ++nt) {
            int n = wave * 64 + nt * 16 + lane15;
            int k = kit * 32 + quad * 8;
            B[kit][nt] = *(const bf16x8*)(w1bf + n * K2 + k);
        }

    float b1v[4], w2v[4];
#pragma unroll
    for (int nt = 0; nt < 4; ++nt) {
        int n = wave * 64 + nt * 16 + lane15;
        b1v[nt] = b1[n];
        w2v[nt] = w2[n];
    }
    const float b2 = *b2p;

    const int r_off = tid >> 5;
    const int c = (tid & 31) ^ (r_off & 7);
    const int half = c >> 4;
    const int fc = c & 15;
    const int* idx_base = half ? dstE : srcE;
    const int gshort = fc * 8;

    const int t0 = blockIdx.x;
    int inode[4];

#pragma unroll
    for (int it = 0; it < 4; ++it)
        inode[it] = idx_base[t0 * TILE_M + it * 8 + r_off];
#pragma unroll
    for (int it = 0; it < 4; ++it)
        __builtin_amdgcn_global_load_lds(
            (gas_t)(hbf + inode[it] * D + gshort),
            (las_t)(&X[0][0] + it * 2048 + wave * 512), 16, 0, 0);
    {
        const int t1 = t0 + GRID;
#pragma unroll
        for (int it = 0; it < 4; ++it)
            inode[it] = idx_base[t1 * TILE_M + it * 8 + r_off];
    }

    int buf = 0;
    int prev_eb = -1;

    for (int tile = t0; tile < NTILES; tile += GRID) {
        __syncthreads();

        const int nt1 = tile + GRID;
        if (nt1 < NTILES) {
            unsigned short* Xn = &X[buf ^ 1][0];
#pragma unroll
            for (int it = 0; it < 4; ++it)
                __builtin_amdgcn_global_load_lds(
                    (gas_t)(hbf + inode[it] * D + gshort),
                    (las_t)(Xn + it * 2048 + wave * 512), 16, 0, 0);
        }
        const int nt2 = tile + 2 * GRID;
        if (nt2 < NTILES) {
            const int eb2 = nt2 * TILE_M;
#pragma unroll
            for (int it = 0; it < 4; ++it)
                inode[it] = idx_base[eb2 + it * 8 + r_off];
        }
        if (prev_eb >= 0 && tid < TILE_M) {
            float s = b2;
#pragma unroll
            for (int w = 0; w < 4; ++w) s += red[buf ^ 1][tid][w];
            out[prev_eb + tid] = s;
        }

        const unsigned short* Xc = &X[buf][0];
        f32x4 acc[2][4];
        const f32x4 zero = {0.f, 0.f, 0.f, 0.f};
#pragma unroll
        for (int ms = 0; ms < 2; ++ms)
#pragma unroll
            for (int nt = 0; nt < 4; ++nt)
                acc[ms][nt] = zero;

#pragma unroll
        for (int kit = 0; kit < 8; ++kit) {
            const int p8 = (((kit * 4 + quad) ^ (lane15 & 7))) * 8;
            bf16x8 a[2];
#pragma unroll
            for (int ms = 0; ms < 2; ++ms)
                a[ms] = *(const bf16x8*)&Xc[(ms * 16 + lane15) * K2 + p8];
#pragma unroll
            for (int ms = 0; ms < 2; ++ms)
#pragma unroll
                for (int nt = 0; nt < 4; ++nt)
                    acc[ms][nt] = __builtin_amdgcn_mfma_f32_16x16x32_bf16(
                        a[ms], B[kit][nt], acc[ms][nt], 0, 0, 0);
        }

#pragma unroll
        for (int ms = 0; ms < 2; ++ms)
#pragma unroll
            for (int r = 0; r < 4; ++r) {
                float p = 0.f;
#pragma unroll
                for (int nt = 0; nt < 4; ++nt) {
                    float hv = acc[ms][nt][r] + b1v[nt];
                    p = fmaf(fmaxf(hv, 0.f), w2v[nt], p);
                }
                p += __shfl_xor(p, 1, 16);
                p += __shfl_xor(p, 2, 16);
                p += __shfl_xor(p, 4, 16);
                p += __shfl_xor(p, 8, 16);
                if (lane15 == 0) red[buf][ms * 16 + quad * 4 + r][wave] = p;
            }
        prev_eb = tile * TILE_M;
        buf ^= 1;
    }

    __syncthreads();
    if (prev_eb >= 0 && tid < TILE_M) {
        float s = b2;
#pragma unroll
        for (int w = 0; w < 4; ++w) s += red[buf ^ 1][tid][w];
        out[prev_eb + tid] = s;
    }
}

// ================================ launch ================================

extern "C" void kernel_launch(void* const* d_in, const int* in_sizes, int n_in,
                              void* d_out, int out_size, void* d_ws, size_t ws_size,
                              hipStream_t stream) {
    const float* h    = (const float*)d_in[0];
    const int*   srcE = (const int*)d_in[1];
    const int*   dstE = (const int*)d_in[2];
    const float* W1   = (const float*)d_in[3];
    const float* b1   = (const float*)d_in[4];
    const float* w2   = (const float*)d_in[5];
    const float* b2   = (const float*)d_in[6];
    float* out = (float*)d_out;

    const size_t planeElems = (size_t)NNODES * H;        // 25.6M
    const size_t need = planeElems * 2 * sizeof(unsigned short);  // 102.4 MB

    if (ws_size >= need) {
        unsigned short* Us = (unsigned short*)d_ws;
        unsigned short* Ud = Us + planeElems;
        u_gemm<<<(NNODES + 63) / 64, 256, 0, stream>>>(h, W1, b1, Us, Ud);
        edge_score<<<4096, 256, 0, stream>>>(Us, Ud, srcE, dstE, w2, b2, out);
    } else {
        unsigned short* hbf  = (unsigned short*)d_ws;
        unsigned short* w1bf = hbf + (size_t)NNODES * D;
        int n4h = NNODES * D / 4;
        int n4w = H * K2 / 4;
        int n4 = n4h + n4w;
        cvt_kernel<<<(n4 + 255) / 256, 256, 0, stream>>>(h, W1, hbf, w1bf, n4h, n4w);
        edge_mlp<<<GRID, 256, 0, stream>>>(hbf, srcE, dstE, w1bf, b1, w2, b2, out);
    }
}